// Round 4
// baseline (325.146 us; speedup 1.0000x reference)
//
#include <hip/hip_runtime.h>
#include <stdint.h>

// Problem constants (B=4, S=4096, D_IN=2048, D_OUT=2048, DELTA_A=0, DELTA_W=0.05)
#define K_DIM   2048
#define N_DIM   2048
#define M_DIM   16384   // B*S
#define DELTA_W 0.05f

// R6: register-pipelined 3-buffer schedule at R5 geometry.
// R5 counters (MfmaUtil 31% despite 2 blocks/CU, nothing saturated) showed
// the 2-phase {stage->vmcnt+bar->read->MFMA->bar} serialization is the
// bottleneck, not occupancy. This schedule gives each group: sub1 MFMA from
// registers (no deps) || staged loads in flight; ONE vmcnt(3)+barrier whose
// wait is free (loads 2 groups old); prefetch ds_reads with no same-group
// consumer; sub2 MFMA. Matrix pipe sees work in every window.
#define BM 128
#define BN 256
#define BK 64
#define NT (K_DIM / BK)   // 32 K-tiles

typedef __attribute__((ext_vector_type(4))) int i32x4;

// ---------------------------------------------------------------------------
// async global->LDS, 16B per lane. LDS dest must be wave-uniform base + lane*16.
__device__ __forceinline__ void async_copy16(const void* g, void* l) {
    __builtin_amdgcn_global_load_lds(
        (__attribute__((address_space(1))) void*)g,
        (__attribute__((address_space(3))) void*)l,
        16, 0, 0);
}

// 256-thread block sum (4 waves of 64)
__device__ __forceinline__ float block_sum_256(float v, float* sm) {
#pragma unroll
    for (int o = 32; o > 0; o >>= 1) v += __shfl_down(v, o, 64);
    const int lane = threadIdx.x & 63;
    const int w    = threadIdx.x >> 6;
    __syncthreads();              // protect sm reuse across calls
    if (lane == 0) sm[w] = v;
    __syncthreads();
    return sm[0] + sm[1] + sm[2] + sm[3];
}

// ---------------------------------------------------------------------------
// Fused quantization kernel (unchanged — verified, not the bottleneck).
__global__ __launch_bounds__(256) void quant_kernel(
    const float* __restrict__ W, const float* __restrict__ x,
    int8_t* __restrict__ code, float* __restrict__ alpha,
    int8_t* __restrict__ xq)
{
    __shared__ float sm[4];
    const int t = threadIdx.x;

    if (blockIdx.x < N_DIM) {
        // ---- weight ternarization ----
        const int row = blockIdx.x;
        const float* Wr = W + (size_t)row * K_DIM;

        float v[8];
        float s = 0.f;
#pragma unroll
        for (int i = 0; i < 8; ++i) { v[i] = Wr[t + i * 256]; s += v[i]; }
        const float mean = block_sum_256(s, sm) * (1.0f / K_DIM);

        float sa = 0.f;
#pragma unroll
        for (int i = 0; i < 8; ++i) sa += fabsf(v[i] - mean);
        const float thr = DELTA_W * (block_sum_256(sa, sm) * (1.0f / K_DIM));

        float ssum = 0.f, scnt = 0.f;
        int8_t q[8];
#pragma unroll
        for (int i = 0; i < 8; ++i) {
            const float c = v[i] - mean;
            const float a = fabsf(c);
            int8_t qv = 0;
            if (a >= thr) qv = (int8_t)((c > 0.f) - (c < 0.f));
            q[i] = qv;
            if (qv != 0) { ssum += a; scnt += 1.0f; }
        }
        const float num = block_sum_256(ssum, sm);
        const float den = block_sum_256(scnt, sm);
        if (t == 0) alpha[row] = num / fmaxf(den, 1.0f);

#pragma unroll
        for (int i = 0; i < 8; ++i)
            code[(size_t)row * K_DIM + t + i * 256] = q[i];
    } else {
        // ---- activation sign pass: 4 float4 per thread, coalesced ----
        const int blk = blockIdx.x - N_DIM;       // 0..8191
        const int base = blk * 1024 + t;          // float4-group index
        const float4* xin = (const float4*)x;
        char4* xo = (char4*)xq;
#pragma unroll
        for (int i = 0; i < 4; ++i) {
            const float4 f = xin[base + i * 256];
            char4 c;
            c.x = (char)((f.x > 0.f) - (f.x < 0.f));
            c.y = (char)((f.y > 0.f) - (f.y < 0.f));
            c.z = (char)((f.z > 0.f) - (f.z < 0.f));
            c.w = (char)((f.w > 0.f) - (f.w < 0.f));
            xo[base + i * 256] = c;
        }
    }
}

// ---------------------------------------------------------------------------
// Ternary GEMM, 128x256 tile, BK=64, 3-buffer register-pipelined schedule.
//
// Geometry (R5-verified): 512 threads = 8 waves (2M x 4N), per-wave 64x64 =
// 4x4 grid of 16x16x64 i8 MFMAs. LDS: 3 buffers x (A 8KiB + B 16KiB) = 72KiB.
// Tile tau lives in buffer tau%3.
//
// LDS swizzle (R5-verified, 0 conflicts): 64B rows, 4 chunks of 16B; chunk
// cg of row r at slot cg ^ ((r>>1)&3), applied on the GLOBAL source address
// (global_load_lds needs lane-linear LDS dest); reads XOR the same key.
//
// Schedule per group t (ledger proven in journal):
//   STAGE(t+2 -> buf[(t+2)%3])       3 vmem issues; WAR-safe: that buffer's
//                                    tile t-1 reads happened before group
//                                    t-1's barrier (data-dep drained)
//   sub1: 8 MFMA (af[0..1] x bf)     pure registers, read last group
//   vmcnt(3); s_barrier              drains tile t+1's loads (issued 2
//                                    groups = ~3400cy back >> HBM 900cy ->
//                                    wait ~ free); newest 3 (t+2) in flight
//   ds_read ALL 8 frags of tile t+1  no consumer this group -> latency free
//   sub2: 8 MFMA (af[2..3] x bf)
// ONE barrier per K-tile. Frag sets ping-pong af[2][4]/bf[2][4]; explicit
// 6-group unroll makes parity (t&1) and buffer (t%3) compile-time.
__global__ __launch_bounds__(512, 2) void gemm_kernel(
    const int8_t* __restrict__ A, const int8_t* __restrict__ Bt,
    const float* __restrict__ alpha, const float* __restrict__ bias,
    float* __restrict__ out)
{
    __shared__ __align__(16) int8_t As[3][BM * BK];   // 3 x 8 KiB
    __shared__ __align__(16) int8_t Bs[3][BN * BK];   // 3 x 16 KiB

    const int tid  = threadIdx.x;          // 0..511
    const int lane = tid & 63;
    const int wv   = tid >> 6;             // wave 0..7
    const int wm   = (wv >> 2) * 64;       // wave m-offset: 0 / 64
    const int wn   = (wv & 3) * 64;        // wave n-offset: 0,64,128,192
    const int fr   = lane & 15;            // fragment row within 16
    const int q    = lane >> 4;            // k-quad 0..3 (16B each)
    const int cs16 = (q ^ ((fr >> 1) & 3)) * 16;  // swizzled chunk byte-off

    // XCD-chunked block swizzle (T1, bijective: 1024 = 8 XCD x 128) —
    // R5-verified: FETCH_SIZE 135MB -> 49MB.
    const int bid = blockIdx.x;
    const int xcd = bid & 7;
    const int idx = bid >> 3;              // 0..127 within XCD
    const int tileN = (idx & 7) * BN;
    const int tileM = ((idx >> 3) + (xcd << 4)) * BM;

    // staging source byte offsets (R5-verified): slot s, row r=s>>2,
    // global chunk cg = (s&3) ^ ((r>>1)&3) (inverse swizzle).
    const int ra = tid >> 2;                       // A row 0..127
    const int ca = (tid & 3) ^ ((ra >> 1) & 3);
    const unsigned a_off = (unsigned)(tileM + ra) * K_DIM + ca * 16;
    unsigned b_off[2];
#pragma unroll
    for (int e = 0; e < 2; ++e) {
        const int s  = e * 512 + tid;
        const int rb = s >> 2;                     // B row 0..255
        const int cb = (s & 3) ^ ((rb >> 1) & 3);
        b_off[e] = (unsigned)(tileN + rb) * K_DIM + cb * 16;
    }

    i32x4 acc[4][4] = {};
    i32x4 af[2][4], bf[2][4];   // ping-pong fragment sets

#define STAGE(BC, kk0) do {                                                    \
    async_copy16(A  + a_off    + (kk0), &As[BC][tid * 16]);                    \
    async_copy16(Bt + b_off[0] + (kk0), &Bs[BC][tid * 16]);                    \
    async_copy16(Bt + b_off[1] + (kk0), &Bs[BC][8192 + tid * 16]);             \
} while (0)

#define RD(P, BC) {                                                            \
    _Pragma("unroll")                                                          \
    for (int i = 0; i < 4; ++i)                                                \
        af[P][i] = *(const i32x4*)(&As[BC][(wm + i * 16 + fr) * 64] + cs16);   \
    _Pragma("unroll")                                                          \
    for (int j = 0; j < 4; ++j)                                                \
        bf[P][j] = *(const i32x4*)(&Bs[BC][(wn + j * 16 + fr) * 64] + cs16);   \
}

#define SUBMM(P, I0) {                                                         \
    _Pragma("unroll")                                                          \
    for (int i = I0; i < I0 + 2; ++i) {                                        \
        _Pragma("unroll")                                                      \
        for (int j = 0; j < 4; ++j)                                            \
            acc[i][j] = __builtin_amdgcn_mfma_i32_16x16x64_i8(                 \
                af[P][i], bf[P][j], acc[i][j], 0, 0, 0);                       \
    }                                                                          \
}

// GROUP(t): T=tile idx, P=t&1 (cur frag set), BNX=(t+1)%3 (next-tile buf),
// BS=(t+2)%3 (stage buf), DS=stage?, WV=vmcnt literal.
#define GROUP(T, P, BNX, BS, DS, WV) {                                         \
    if (DS) { STAGE(BS, (T + 2) * BK); }                                       \
    SUBMM(P, 0);                                                               \
    asm volatile("s_waitcnt vmcnt(" WV ")\n\ts_barrier" ::: "memory");         \
    RD(P ^ 1, BNX);                                                            \
    SUBMM(P, 2);                                                               \
}

    // ---- prologue: stage tiles 0,1; wait tile 0; read its frags ----
    STAGE(0, 0);
    STAGE(1, BK);
    asm volatile("s_waitcnt vmcnt(3)\n\ts_barrier" ::: "memory");
    RD(0, 0);
    // entry state for t=0: cur=set0=tile0, outstanding=3 (tile1's loads)

#pragma unroll 1
    for (int u = 0; u < 5; ++u) {      // groups t = 0..29 (6 per iteration)
        const int t6 = u * 6;
        GROUP(t6 + 0, 0, 1, 2, 1, "3");
        GROUP(t6 + 1, 1, 2, 0, 1, "3");
        GROUP(t6 + 2, 0, 0, 1, 1, "3");
        GROUP(t6 + 3, 1, 1, 2, 1, "3");
        GROUP(t6 + 4, 0, 2, 0, 1, "3");
        GROUP(t6 + 5, 1, 0, 1, 1, "3");
    }
    // t=30: no stage; vmcnt(0) drains tile31's loads; read tile31 from buf 1
    GROUP(30, 0, 1, 0, 0, "0");
    // t=31: MFMA only (frags in set1)
    SUBMM(1, 0);
    SUBMM(1, 2);

#undef GROUP
#undef SUBMM
#undef RD
#undef STAGE

    // ---- epilogue: C/D layout col=lane&15, row=(lane>>4)*4+reg ----
    const int cl = lane & 15;
    const int qr = lane >> 4;
#pragma unroll
    for (int j = 0; j < 4; ++j) {
        const int n  = tileN + wn + j * 16 + cl;
        const float al = alpha[n];
        const float bi = bias[n];
#pragma unroll
        for (int i = 0; i < 4; ++i) {
            const int mbase = tileM + wm + i * 16 + qr * 4;
#pragma unroll
            for (int r = 0; r < 4; ++r) {
                out[(size_t)(mbase + r) * N_DIM + n] =
                    al * (float)acc[i][j][r] + bi;
            }
        }
    }
}

// ---------------------------------------------------------------------------
extern "C" void kernel_launch(void* const* d_in, const int* in_sizes, int n_in,
                              void* d_out, int out_size, void* d_ws, size_t ws_size,
                              hipStream_t stream) {
    const float* x = (const float*)d_in[0];   // [4,4096,2048] fp32
    const float* W = (const float*)d_in[1];   // [2048,2048]  fp32
    const float* b = (const float*)d_in[2];   // [2048]       fp32
    float* out = (float*)d_out;               // [4,4096,2048] fp32

    // workspace layout: xq (32 MiB) | wcode (4 MiB) | alpha (8 KiB)
    int8_t* xq    = (int8_t*)d_ws;
    int8_t* wcode = xq + (size_t)M_DIM * K_DIM;
    float*  alpha = (float*)(wcode + (size_t)N_DIM * K_DIM);

    // 2048 wquant blocks + 8192 xquant blocks in one launch
    quant_kernel<<<N_DIM + 8192, 256, 0, stream>>>(W, x, wcode, alpha, xq);

    // 1-D grid, XCD-chunk swizzled inside the kernel: (M/128)*(N/256) = 1024
    gemm_kernel<<<1024, dim3(512), 0, stream>>>(xq, wcode, alpha, b, out);
}

// Round 5
// 305.736 us; speedup vs baseline: 1.0635x; 1.0635x over previous
//
#include <hip/hip_runtime.h>
#include <stdint.h>

// Problem constants (B=4, S=4096, D_IN=2048, D_OUT=2048, DELTA_A=0, DELTA_W=0.05)
#define K_DIM   2048
#define N_DIM   2048
#define M_DIM   16384   // B*S
#define DELTA_W 0.05f

// R7: faithful 8-phase 256^2 schedule (T3+T4+T5) at i8 BK=128.
// Byte-isomorphic to the verified bf16 m201 template (128B rows, 16B chunks,
// 16KB half-tiles). R3's race is fixed by staging tile t+2 INTO the buffer
// being read, at phases where that region's reads have provably completed
// (B' at ph3, A' at ph4), with counted vmcnt(8) fused barriers at ph4/ph8.
#define BM 256
#define BN 256
#define BK 128
#define NT (K_DIM / BK)   // 16 K-tiles, 8 iterations of 2 tiles

typedef __attribute__((ext_vector_type(4))) int i32x4;

// ---------------------------------------------------------------------------
// async global->LDS, 16B per lane. LDS dest must be wave-uniform base + lane*16.
__device__ __forceinline__ void async_copy16(const void* g, void* l) {
    __builtin_amdgcn_global_load_lds(
        (__attribute__((address_space(1))) void*)g,
        (__attribute__((address_space(3))) void*)l,
        16, 0, 0);
}

// 256-thread block sum (4 waves of 64)
__device__ __forceinline__ float block_sum_256(float v, float* sm) {
#pragma unroll
    for (int o = 32; o > 0; o >>= 1) v += __shfl_down(v, o, 64);
    const int lane = threadIdx.x & 63;
    const int w    = threadIdx.x >> 6;
    __syncthreads();              // protect sm reuse across calls
    if (lane == 0) sm[w] = v;
    __syncthreads();
    return sm[0] + sm[1] + sm[2] + sm[3];
}

// ---------------------------------------------------------------------------
// Fused quantization kernel (unchanged — verified, not the bottleneck).
__global__ __launch_bounds__(256) void quant_kernel(
    const float* __restrict__ W, const float* __restrict__ x,
    int8_t* __restrict__ code, float* __restrict__ alpha,
    int8_t* __restrict__ xq)
{
    __shared__ float sm[4];
    const int t = threadIdx.x;

    if (blockIdx.x < N_DIM) {
        // ---- weight ternarization ----
        const int row = blockIdx.x;
        const float* Wr = W + (size_t)row * K_DIM;

        float v[8];
        float s = 0.f;
#pragma unroll
        for (int i = 0; i < 8; ++i) { v[i] = Wr[t + i * 256]; s += v[i]; }
        const float mean = block_sum_256(s, sm) * (1.0f / K_DIM);

        float sa = 0.f;
#pragma unroll
        for (int i = 0; i < 8; ++i) sa += fabsf(v[i] - mean);
        const float thr = DELTA_W * (block_sum_256(sa, sm) * (1.0f / K_DIM));

        float ssum = 0.f, scnt = 0.f;
        int8_t q[8];
#pragma unroll
        for (int i = 0; i < 8; ++i) {
            const float c = v[i] - mean;
            const float a = fabsf(c);
            int8_t qv = 0;
            if (a >= thr) qv = (int8_t)((c > 0.f) - (c < 0.f));
            q[i] = qv;
            if (qv != 0) { ssum += a; scnt += 1.0f; }
        }
        const float num = block_sum_256(ssum, sm);
        const float den = block_sum_256(scnt, sm);
        if (t == 0) alpha[row] = num / fmaxf(den, 1.0f);

#pragma unroll
        for (int i = 0; i < 8; ++i)
            code[(size_t)row * K_DIM + t + i * 256] = q[i];
    } else {
        // ---- activation sign pass: 4 float4 per thread, coalesced ----
        const int blk = blockIdx.x - N_DIM;       // 0..8191
        const int base = blk * 1024 + t;          // float4-group index
        const float4* xin = (const float4*)x;
        char4* xo = (char4*)xq;
#pragma unroll
        for (int i = 0; i < 4; ++i) {
            const float4 f = xin[base + i * 256];
            char4 c;
            c.x = (char)((f.x > 0.f) - (f.x < 0.f));
            c.y = (char)((f.y > 0.f) - (f.y < 0.f));
            c.z = (char)((f.z > 0.f) - (f.z < 0.f));
            c.w = (char)((f.w > 0.f) - (f.w < 0.f));
            xo[base + i * 256] = c;
        }
    }
}

// ---------------------------------------------------------------------------
// Ternary GEMM, 256^2 tile, BK=128, 8-phase schedule with counted vmcnt.
//
// Geometry (R4-verified math): 512 threads = 8 waves (2M x 4N), per-wave
// output 128x64; acc[8][4] of 16x16 frags. LDS: 2 dbuf x (A 32K + B 32K)
// = 128 KiB. Iteration = 2 K-tiles: T_even in dbuf0, T_odd in dbuf1.
//
// Per phase p (quadrants (m0,n0),(m0,n1),(m1,n1),(m1,n0) per K-tile):
//   { ds_read this quadrant's frags | stage half-tiles of tile t+2 }
//   s_barrier
//   s_waitcnt lgkmcnt(0); sched_barrier(0)      <- rule #18
//   setprio(1); 16 x mfma_i32_16x16x64_i8; setprio(0)
//   s_barrier                                    (ph4/ph8: vmcnt(8)+barrier)
//
// Stage placement (into the dbuf being READ — safe by read-completion):
//   B-halves of dbuf D are fully consumed by ph2's MFMAs (reads ph1/ph2,
//   data-dep drained before each wave's ph2-end barrier) -> stage B' at ph3.
//   A-halves consumed by ph3's MFMAs -> stage A' at ph4.
// Ledger (steady state): entering ph1 in-flight=8 (other dbuf's tile);
// ph3 +4, ph4 +4 -> 16 -> vmcnt(8) drains the 8 oldest (= the tile ph5
// reads; issued 4-5 phases back >> HBM latency -> free wait), leaves 8
// (this dbuf's t+2, read only after next vmcnt(8)). Symmetric at ph8.
// Never drains to 0 in the main loop. Last iteration stages nothing:
// ph4 waits vmcnt(0) (loads 4-5 phases old), ph8 plain barrier.
__global__ __launch_bounds__(512, 2) void gemm_kernel(
    const int8_t* __restrict__ A, const int8_t* __restrict__ Bt,
    const float* __restrict__ alpha, const float* __restrict__ bias,
    float* __restrict__ out)
{
    __shared__ __align__(16) int8_t As[2][BM * BK];   // 2 x 32 KiB
    __shared__ __align__(16) int8_t Bs[2][BN * BK];   // 2 x 32 KiB

    const int tid  = threadIdx.x;          // 0..511
    const int lane = tid & 63;
    const int wv   = tid >> 6;             // wave 0..7
    const int wm   = (wv >> 2) * 128;      // wave m-offset: 0 / 128
    const int wn   = (wv & 3) * 64;        // wave n-offset: 0,64,128,192
    const int fr   = lane & 15;            // fragment row within 16
    const int q    = lane >> 4;            // k-quad 0..3 (16B each)
    const int x0   = (q ^ (fr & 7)) * 16;  // swizzled chunk byte-off, kk=0
                                           // kk=1: x0 ^ 64  (R4-verified)

    // XCD-chunked block swizzle (T1, bijective: 512 = 8 XCD x 64; R5-verified
    // FETCH 135->49 MB): per XCD 8 N-tiles x 8 M-tiles, N-fast.
    const int bid = blockIdx.x;
    const int xcd = bid & 7;
    const int idx = bid >> 3;              // 0..63 within XCD
    const int tileN = (idx & 7) * BN;
    const int tileM = ((idx >> 3) + xcd * 8) * BM;

    // staging source byte offsets [half][issue] (R4-verified): slot
    // s=e*512+tid, row r=s>>3 (8 chunks/row), chunk cg=(s&7)^(r&7).
    size_t a_src[2][2], b_src[2][2];
#pragma unroll
    for (int e = 0; e < 2; ++e) {
        const int s  = e * 512 + tid;
        const int r  = s >> 3;
        const int cg = (s & 7) ^ (r & 7);
#pragma unroll
        for (int h = 0; h < 2; ++h) {
            a_src[h][e] = (size_t)(tileM + h * 128 + r) * K_DIM + cg * 16;
            b_src[h][e] = (size_t)(tileN + h * 128 + r) * K_DIM + cg * 16;
        }
    }

    i32x4 acc[8][4] = {};
    i32x4 af[2][4], bf0[2][2], bf1[2][2];  // [kk][frag]

#define STAGE_A(D, h, kk0) do {                                                \
    async_copy16(A  + a_src[h][0] + (kk0), &As[D][(h) * 16384 + tid * 16]);    \
    async_copy16(A  + a_src[h][1] + (kk0),                                     \
                 &As[D][(h) * 16384 + 8192 + tid * 16]);                       \
} while (0)
#define STAGE_B(D, h, kk0) do {                                                \
    async_copy16(Bt + b_src[h][0] + (kk0), &Bs[D][(h) * 16384 + tid * 16]);    \
    async_copy16(Bt + b_src[h][1] + (kk0),                                     \
                 &Bs[D][(h) * 16384 + 8192 + tid * 16]);                       \
} while (0)

#define BARRIER    asm volatile("s_barrier" ::: "memory")
#define VMBAR(W)   asm volatile("s_waitcnt vmcnt(" W ")\n\ts_barrier" ::: "memory")
#define LGKM0      do { asm volatile("s_waitcnt lgkmcnt(0)" ::: "memory");     \
                        __builtin_amdgcn_sched_barrier(0); } while (0)
#define PRIO1      __builtin_amdgcn_s_setprio(1)
#define PRIO0      __builtin_amdgcn_s_setprio(0)

#define RD_AF(Ap, MQ) {                                                        \
    _Pragma("unroll")                                                          \
    for (int i = 0; i < 4; ++i) {                                              \
        const int r8 = (wm + (MQ) * 64 + i * 16 + fr) * 128;                   \
        af[0][i] = *(const i32x4*)((Ap) + r8 + x0);                            \
        af[1][i] = *(const i32x4*)((Ap) + r8 + (x0 ^ 64));                     \
    }                                                                          \
}
#define RD_BF(Bp, F, NQ) {                                                     \
    _Pragma("unroll")                                                          \
    for (int j = 0; j < 2; ++j) {                                              \
        const int r8 = (wn + (NQ) * 32 + j * 16 + fr) * 128;                   \
        F[0][j] = *(const i32x4*)((Bp) + r8 + x0);                             \
        F[1][j] = *(const i32x4*)((Bp) + r8 + (x0 ^ 64));                      \
    }                                                                          \
}
#define MMQ(F, R, C) {                                                         \
    _Pragma("unroll")                                                          \
    for (int i = 0; i < 4; ++i) {                                              \
        _Pragma("unroll")                                                      \
        for (int j = 0; j < 2; ++j) {                                          \
            acc[(R) + i][(C) + j] = __builtin_amdgcn_mfma_i32_16x16x64_i8(     \
                af[0][i], F[0][j], acc[(R) + i][(C) + j], 0, 0, 0);            \
            acc[(R) + i][(C) + j] = __builtin_amdgcn_mfma_i32_16x16x64_i8(     \
                af[1][i], F[1][j], acc[(R) + i][(C) + j], 0, 0, 0);            \
        }                                                                      \
    }                                                                          \
}

// One K-tile (4 phases) on dbuf D; if DS, stage tile t+2 into the SAME dbuf
// (B' at ph3 after B-reads complete, A' at ph4 after A-reads complete).
// W = vmcnt literal for the fused ph4-end wait.
#define KTILE(Ap, Bp, D, DS, KN, W) {                                          \
    /* ph1: (m0,n0) */                                                         \
    RD_AF(Ap, 0); RD_BF(Bp, bf0, 0);                                           \
    BARRIER; LGKM0; PRIO1; MMQ(bf0, 0, 0); PRIO0; BARRIER;                     \
    /* ph2: (m0,n1) */                                                         \
    RD_BF(Bp, bf1, 1);                                                         \
    BARRIER; LGKM0; PRIO1; MMQ(bf1, 0, 2); PRIO0; BARRIER;                     \
    /* ph3: (m1,n1); stage B' */                                               \
    RD_AF(Ap, 1);                                                              \
    if (DS) { STAGE_B(D, 0, KN); STAGE_B(D, 1, KN); }                          \
    BARRIER; LGKM0; PRIO1; MMQ(bf1, 4, 2); PRIO0; BARRIER;                     \
    /* ph4: (m1,n0); stage A'; counted-vmcnt fused barrier */                  \
    if (DS) { STAGE_A(D, 0, KN); STAGE_A(D, 1, KN); }                          \
    BARRIER; LGKM0; PRIO1; MMQ(bf0, 4, 0); PRIO0; VMBAR(W);                    \
}

    // ---- prologue: stage T0 (dbuf0, first 8 issues) then T1 (dbuf1) ----
    STAGE_A(0, 0, 0); STAGE_A(0, 1, 0); STAGE_B(0, 0, 0); STAGE_B(0, 1, 0);
    STAGE_A(1, 0, BK); STAGE_A(1, 1, BK); STAGE_B(1, 0, BK); STAGE_B(1, 1, BK);
    VMBAR("8");   // T0 resident; T1's 8 loads stay in flight

#pragma unroll 1
    for (int it = 0; it < NT / 2 - 1; ++it) {   // iterations 0..6 stage ahead
        const int kn0 = (2 * it + 2) * BK;
        const int kn1 = (2 * it + 3) * BK;
        KTILE((const int8_t*)As[0], (const int8_t*)Bs[0], 0, 1, kn0, "8");
        KTILE((const int8_t*)As[1], (const int8_t*)Bs[1], 1, 1, kn1, "8");
    }
    // final iteration: no staging; ph4 drains the last tile's loads
    KTILE((const int8_t*)As[0], (const int8_t*)Bs[0], 0, 0, 0, "0");
    KTILE((const int8_t*)As[1], (const int8_t*)Bs[1], 1, 0, 0, "0");

#undef KTILE
#undef MMQ
#undef RD_BF
#undef RD_AF
#undef PRIO0
#undef PRIO1
#undef LGKM0
#undef VMBAR
#undef BARRIER
#undef STAGE_B
#undef STAGE_A

    // ---- epilogue (R4-verified): C/D col=lane&15, row=(lane>>4)*4+reg ----
    const int cl = lane & 15;
    const int qr = lane >> 4;
#pragma unroll
    for (int j = 0; j < 4; ++j) {
        const int n  = tileN + wn + j * 16 + cl;
        const float al = alpha[n];
        const float bi = bias[n];
#pragma unroll
        for (int i = 0; i < 8; ++i) {
            const int mbase = tileM + wm + i * 16 + qr * 4;
#pragma unroll
            for (int r = 0; r < 4; ++r) {
                out[(size_t)(mbase + r) * N_DIM + n] =
                    al * (float)acc[i][j][r] + bi;
            }
        }
    }
}

// ---------------------------------------------------------------------------
extern "C" void kernel_launch(void* const* d_in, const int* in_sizes, int n_in,
                              void* d_out, int out_size, void* d_ws, size_t ws_size,
                              hipStream_t stream) {
    const float* x = (const float*)d_in[0];   // [4,4096,2048] fp32
    const float* W = (const float*)d_in[1];   // [2048,2048]  fp32
    const float* b = (const float*)d_in[2];   // [2048]       fp32
    float* out = (float*)d_out;               // [4,4096,2048] fp32

    // workspace layout: xq (32 MiB) | wcode (4 MiB) | alpha (8 KiB)
    int8_t* xq    = (int8_t*)d_ws;
    int8_t* wcode = xq + (size_t)M_DIM * K_DIM;
    float*  alpha = (float*)(wcode + (size_t)N_DIM * K_DIM);

    // 2048 wquant blocks + 8192 xquant blocks in one launch
    quant_kernel<<<N_DIM + 8192, 256, 0, stream>>>(W, x, wcode, alpha, xq);

    // 1-D grid, XCD-chunk swizzled in-kernel: (M/256)*(N/256) = 512 blocks
    gemm_kernel<<<512, dim3(512), 0, stream>>>(xq, wcode, alpha, b, out);
}

// Round 6
// 301.183 us; speedup vs baseline: 1.0796x; 1.0151x over previous
//
#include <hip/hip_runtime.h>
#include <stdint.h>

// Problem constants (B=4, S=4096, D_IN=2048, D_OUT=2048, DELTA_A=0, DELTA_W=0.05)
#define K_DIM   2048
#define N_DIM   2048
#define M_DIM   16384   // B*S
#define DELTA_W 0.05f

// R8: R7's 8-phase 256^2 i8 schedule with the sync skeleton relaxed.
// R7 counters (MfmaUtil 33%, ~900cy/phase overhead vs ~650cy MFMA) showed
// the phases themselves stalled on my sync macros: per-phase sched_barrier(0)
// (only needed for inline-asm ds_reads — ours are IR loads; m141: order-
// pinning regresses) and a redundant start-barrier. One barrier per phase
// suffices: lgkmcnt(0) BEFORE the end barrier guarantees each phase's LDS
// reads are drained chip-wide at the barrier (immune to reg-only MFMA
// sinking, rule #18 dual), and stage targets only overwrite regions whose
// reads ended >=1 end-barrier earlier (B' at ph3: all B reads done ph2-end;
// A' at ph4: all A reads done ph3-end). vmcnt ledger identical to R7.
#define BM 256
#define BN 256
#define BK 128
#define NT (K_DIM / BK)   // 16 K-tiles, 8 iterations of 2 tiles

typedef __attribute__((ext_vector_type(4))) int i32x4;

// ---------------------------------------------------------------------------
// async global->LDS, 16B per lane. LDS dest must be wave-uniform base + lane*16.
__device__ __forceinline__ void async_copy16(const void* g, void* l) {
    __builtin_amdgcn_global_load_lds(
        (__attribute__((address_space(1))) void*)g,
        (__attribute__((address_space(3))) void*)l,
        16, 0, 0);
}

// 256-thread block sum (4 waves of 64)
__device__ __forceinline__ float block_sum_256(float v, float* sm) {
#pragma unroll
    for (int o = 32; o > 0; o >>= 1) v += __shfl_down(v, o, 64);
    const int lane = threadIdx.x & 63;
    const int w    = threadIdx.x >> 6;
    __syncthreads();              // protect sm reuse across calls
    if (lane == 0) sm[w] = v;
    __syncthreads();
    return sm[0] + sm[1] + sm[2] + sm[3];
}

// ---------------------------------------------------------------------------
// Fused quantization kernel (unchanged — verified, not the bottleneck).
__global__ __launch_bounds__(256) void quant_kernel(
    const float* __restrict__ W, const float* __restrict__ x,
    int8_t* __restrict__ code, float* __restrict__ alpha,
    int8_t* __restrict__ xq)
{
    __shared__ float sm[4];
    const int t = threadIdx.x;

    if (blockIdx.x < N_DIM) {
        // ---- weight ternarization ----
        const int row = blockIdx.x;
        const float* Wr = W + (size_t)row * K_DIM;

        float v[8];
        float s = 0.f;
#pragma unroll
        for (int i = 0; i < 8; ++i) { v[i] = Wr[t + i * 256]; s += v[i]; }
        const float mean = block_sum_256(s, sm) * (1.0f / K_DIM);

        float sa = 0.f;
#pragma unroll
        for (int i = 0; i < 8; ++i) sa += fabsf(v[i] - mean);
        const float thr = DELTA_W * (block_sum_256(sa, sm) * (1.0f / K_DIM));

        float ssum = 0.f, scnt = 0.f;
        int8_t q[8];
#pragma unroll
        for (int i = 0; i < 8; ++i) {
            const float c = v[i] - mean;
            const float a = fabsf(c);
            int8_t qv = 0;
            if (a >= thr) qv = (int8_t)((c > 0.f) - (c < 0.f));
            q[i] = qv;
            if (qv != 0) { ssum += a; scnt += 1.0f; }
        }
        const float num = block_sum_256(ssum, sm);
        const float den = block_sum_256(scnt, sm);
        if (t == 0) alpha[row] = num / fmaxf(den, 1.0f);

#pragma unroll
        for (int i = 0; i < 8; ++i)
            code[(size_t)row * K_DIM + t + i * 256] = q[i];
    } else {
        // ---- activation sign pass: 4 float4 per thread, coalesced ----
        const int blk = blockIdx.x - N_DIM;       // 0..8191
        const int base = blk * 1024 + t;          // float4-group index
        const float4* xin = (const float4*)x;
        char4* xo = (char4*)xq;
#pragma unroll
        for (int i = 0; i < 4; ++i) {
            const float4 f = xin[base + i * 256];
            char4 c;
            c.x = (char)((f.x > 0.f) - (f.x < 0.f));
            c.y = (char)((f.y > 0.f) - (f.y < 0.f));
            c.z = (char)((f.z > 0.f) - (f.z < 0.f));
            c.w = (char)((f.w > 0.f) - (f.w < 0.f));
            xo[base + i * 256] = c;
        }
    }
}

// ---------------------------------------------------------------------------
// Ternary GEMM, 256^2 tile, BK=128, 4-phase/K-tile counted-vmcnt schedule.
//
// Geometry (R4/R7-verified): 512 threads = 8 waves (2M x 4N), per-wave
// output 128x64; acc[8][4] of 16x16 frags. LDS: 2 dbuf x (A 32K + B 32K)
// = 128 KiB. Iteration = 2 K-tiles: T_even in dbuf0, T_odd in dbuf1.
//
// Per phase (quadrants (m0,n0),(m0,n1),(m1,n1),(m1,n0)):
//   { ds_read this quadrant's new frags | stage half-tiles of tile t+2 }
//   setprio(1); 16 x mfma_i32_16x16x64_i8; setprio(0)
//   s_waitcnt lgkmcnt(0)            <- reads drained BEFORE the barrier
//   s_barrier                        (ph4: s_waitcnt vmcnt(8) + s_barrier)
//
// WAR safety (one barrier per phase): stage B' at ph3 — every wave's B
// reads (bf0@ph1 rows wn..wn+31, bf1@ph2 rows wn+32..wn+63, wn spanning
// both global halves) are lgkm-drained at ph2's end barrier. Stage A' at
// ph4 — A reads (ph1 m-half-low, ph3 m-half-high per wave) drained at
// ph3's end barrier. Stage writes land into regions next read 4+ phases
// later, gated by the ph4 vmcnt(8)+barrier (drains the 8 oldest = the
// tile the next 4 phases read; leaves the 8 newest in flight). Never
// drains to 0 mid-loop; last two tiles peel to vmcnt(0).
__global__ __launch_bounds__(512, 2) void gemm_kernel(
    const int8_t* __restrict__ A, const int8_t* __restrict__ Bt,
    const float* __restrict__ alpha, const float* __restrict__ bias,
    float* __restrict__ out)
{
    __shared__ __align__(16) int8_t As[2][BM * BK];   // 2 x 32 KiB
    __shared__ __align__(16) int8_t Bs[2][BN * BK];   // 2 x 32 KiB

    const int tid  = threadIdx.x;          // 0..511
    const int lane = tid & 63;
    const int wv   = tid >> 6;             // wave 0..7
    const int wm   = (wv >> 2) * 128;      // wave m-offset: 0 / 128
    const int wn   = (wv & 3) * 64;        // wave n-offset: 0,64,128,192
    const int fr   = lane & 15;            // fragment row within 16
    const int q    = lane >> 4;            // k-quad 0..3 (16B each)
    const int x0   = (q ^ (fr & 7)) * 16;  // swizzled chunk byte-off, kk=0
                                           // kk=1: x0 ^ 64  (R4-verified)

    // XCD-chunked block swizzle (T1, bijective: 512 = 8 XCD x 64; R5-verified
    // FETCH 135->49 MB): per XCD 8 N-tiles x 8 M-tiles, N-fast.
    const int bid = blockIdx.x;
    const int xcd = bid & 7;
    const int idx = bid >> 3;              // 0..63 within XCD
    const int tileN = (idx & 7) * BN;
    const int tileM = ((idx >> 3) + xcd * 8) * BM;

    // staging source byte offsets [half][issue] (R4-verified): slot
    // s=e*512+tid, row r=s>>3 (8 chunks/row), chunk cg=(s&7)^(r&7).
    size_t a_src[2][2], b_src[2][2];
#pragma unroll
    for (int e = 0; e < 2; ++e) {
        const int s  = e * 512 + tid;
        const int r  = s >> 3;
        const int cg = (s & 7) ^ (r & 7);
#pragma unroll
        for (int h = 0; h < 2; ++h) {
            a_src[h][e] = (size_t)(tileM + h * 128 + r) * K_DIM + cg * 16;
            b_src[h][e] = (size_t)(tileN + h * 128 + r) * K_DIM + cg * 16;
        }
    }

    i32x4 acc[8][4] = {};
    i32x4 af[2][4], bf0[2][2], bf1[2][2];  // [kk][frag]

#define STAGE_A(D, h, kk0) do {                                                \
    async_copy16(A  + a_src[h][0] + (kk0), &As[D][(h) * 16384 + tid * 16]);    \
    async_copy16(A  + a_src[h][1] + (kk0),                                     \
                 &As[D][(h) * 16384 + 8192 + tid * 16]);                       \
} while (0)
#define STAGE_B(D, h, kk0) do {                                                \
    async_copy16(Bt + b_src[h][0] + (kk0), &Bs[D][(h) * 16384 + tid * 16]);    \
    async_copy16(Bt + b_src[h][1] + (kk0),                                     \
                 &Bs[D][(h) * 16384 + 8192 + tid * 16]);                       \
} while (0)

#define BARRIER    asm volatile("s_barrier" ::: "memory")
#define VMBAR(W)   asm volatile("s_waitcnt vmcnt(" W ")\n\ts_barrier" ::: "memory")
// drain this phase's LDS reads BEFORE the end barrier (WAR guarantee that
// survives reg-only MFMA sinking; no sched_barrier — let the compiler
// interleave fine-grained lgkmcnt waits with the MFMA cluster)
#define LGKME      asm volatile("s_waitcnt lgkmcnt(0)" ::: "memory")
#define PRIO1      __builtin_amdgcn_s_setprio(1)
#define PRIO0      __builtin_amdgcn_s_setprio(0)

#define RD_AF(Ap, MQ) {                                                        \
    _Pragma("unroll")                                                          \
    for (int i = 0; i < 4; ++i) {                                              \
        const int r8 = (wm + (MQ) * 64 + i * 16 + fr) * 128;                   \
        af[0][i] = *(const i32x4*)((Ap) + r8 + x0);                            \
        af[1][i] = *(const i32x4*)((Ap) + r8 + (x0 ^ 64));                     \
    }                                                                          \
}
#define RD_BF(Bp, F, NQ) {                                                     \
    _Pragma("unroll")                                                          \
    for (int j = 0; j < 2; ++j) {                                              \
        const int r8 = (wn + (NQ) * 32 + j * 16 + fr) * 128;                   \
        F[0][j] = *(const i32x4*)((Bp) + r8 + x0);                             \
        F[1][j] = *(const i32x4*)((Bp) + r8 + (x0 ^ 64));                      \
    }                                                                          \
}
#define MMQ(F, R, C) {                                                         \
    _Pragma("unroll")                                                          \
    for (int i = 0; i < 4; ++i) {                                              \
        _Pragma("unroll")                                                      \
        for (int j = 0; j < 2; ++j) {                                          \
            acc[(R) + i][(C) + j] = __builtin_amdgcn_mfma_i32_16x16x64_i8(     \
                af[0][i], F[0][j], acc[(R) + i][(C) + j], 0, 0, 0);            \
            acc[(R) + i][(C) + j] = __builtin_amdgcn_mfma_i32_16x16x64_i8(     \
                af[1][i], F[1][j], acc[(R) + i][(C) + j], 0, 0, 0);            \
        }                                                                      \
    }                                                                          \
}

// One K-tile (4 phases) on dbuf D; if DS, stage tile t+2 into the SAME dbuf
// (B' at ph3, A' at ph4 — after those regions' reads have drained).
// W = vmcnt literal for the fused ph4-end wait.
#define KTILE(Ap, Bp, D, DS, KN, W) {                                          \
    /* ph1: (m0,n0) */                                                         \
    RD_AF(Ap, 0); RD_BF(Bp, bf0, 0);                                           \
    PRIO1; MMQ(bf0, 0, 0); PRIO0; LGKME; BARRIER;                              \
    /* ph2: (m0,n1) */                                                         \
    RD_BF(Bp, bf1, 1);                                                         \
    PRIO1; MMQ(bf1, 0, 2); PRIO0; LGKME; BARRIER;                              \
    /* ph3: (m1,n1); stage B' (B reads all drained at ph2-end) */              \
    RD_AF(Ap, 1);                                                              \
    if (DS) { STAGE_B(D, 0, KN); STAGE_B(D, 1, KN); }                          \
    PRIO1; MMQ(bf1, 4, 2); PRIO0; LGKME; BARRIER;                              \
    /* ph4: (m1,n0); stage A' (A reads drained at ph3-end); counted vmcnt */   \
    if (DS) { STAGE_A(D, 0, KN); STAGE_A(D, 1, KN); }                          \
    PRIO1; MMQ(bf0, 4, 0); PRIO0; LGKME; VMBAR(W);                             \
}

    // ---- prologue: stage T0 (dbuf0, first 8 issues) then T1 (dbuf1) ----
    STAGE_A(0, 0, 0); STAGE_A(0, 1, 0); STAGE_B(0, 0, 0); STAGE_B(0, 1, 0);
    STAGE_A(1, 0, BK); STAGE_A(1, 1, BK); STAGE_B(1, 0, BK); STAGE_B(1, 1, BK);
    VMBAR("8");   // T0 resident; T1's 8 loads stay in flight

#pragma unroll 1
    for (int it = 0; it < NT / 2 - 1; ++it) {   // iterations 0..6 stage ahead
        const int kn0 = (2 * it + 2) * BK;
        const int kn1 = (2 * it + 3) * BK;
        KTILE((const int8_t*)As[0], (const int8_t*)Bs[0], 0, 1, kn0, "8");
        KTILE((const int8_t*)As[1], (const int8_t*)Bs[1], 1, 1, kn1, "8");
    }
    // final iteration: no staging; tile 14's ph4 drains tile 15's loads
    KTILE((const int8_t*)As[0], (const int8_t*)Bs[0], 0, 0, 0, "0");
    KTILE((const int8_t*)As[1], (const int8_t*)Bs[1], 1, 0, 0, "0");

#undef KTILE
#undef MMQ
#undef RD_BF
#undef RD_AF
#undef PRIO0
#undef PRIO1
#undef LGKME
#undef VMBAR
#undef BARRIER
#undef STAGE_B
#undef STAGE_A

    // ---- epilogue (R4-verified): C/D col=lane&15, row=(lane>>4)*4+reg ----
    const int cl = lane & 15;
    const int qr = lane >> 4;
#pragma unroll
    for (int j = 0; j < 4; ++j) {
        const int n  = tileN + wn + j * 16 + cl;
        const float al = alpha[n];
        const float bi = bias[n];
#pragma unroll
        for (int i = 0; i < 8; ++i) {
            const int mbase = tileM + wm + i * 16 + qr * 4;
#pragma unroll
            for (int r = 0; r < 4; ++r) {
                out[(size_t)(mbase + r) * N_DIM + n] =
                    al * (float)acc[i][j][r] + bi;
            }
        }
    }
}

// ---------------------------------------------------------------------------
extern "C" void kernel_launch(void* const* d_in, const int* in_sizes, int n_in,
                              void* d_out, int out_size, void* d_ws, size_t ws_size,
                              hipStream_t stream) {
    const float* x = (const float*)d_in[0];   // [4,4096,2048] fp32
    const float* W = (const float*)d_in[1];   // [2048,2048]  fp32
    const float* b = (const float*)d_in[2];   // [2048]       fp32
    float* out = (float*)d_out;               // [4,4096,2048] fp32

    // workspace layout: xq (32 MiB) | wcode (4 MiB) | alpha (8 KiB)
    int8_t* xq    = (int8_t*)d_ws;
    int8_t* wcode = xq + (size_t)M_DIM * K_DIM;
    float*  alpha = (float*)(wcode + (size_t)N_DIM * K_DIM);

    // 2048 wquant blocks + 8192 xquant blocks in one launch
    quant_kernel<<<N_DIM + 8192, 256, 0, stream>>>(W, x, wcode, alpha, xq);

    // 1-D grid, XCD-chunk swizzled in-kernel: (M/256)*(N/256) = 512 blocks
    gemm_kernel<<<512, dim3(512), 0, stream>>>(xq, wcode, alpha, b, out);
}